// Round 13
// baseline (964.709 us; speedup 1.0000x reference)
//
#include <hip/hip_runtime.h>
#include <math.h>

// VectorQuantization: B=8192 rows, N=8192 codes, D=512
// out = [quantized (B*D) | ind (B, as float) | loss (B)]
constexpr int B = 8192, N = 8192, D = 512;
constexpr float EPSF = 1e-20f;
constexpr float SKIP   = 20.0f;  // exp(-20) ~ 2e-9: safely negligible
constexpr float GMAX   = 17.0f;  // -log(-log(u+eps)) <= 16.7 for fp32 u in [0,1)
constexpr float DELTAF = 1.0f;   // single-product bf16 dist gate (~14 sigma)
constexpr float DELTA  = 0.05f;  // fallback-path dist gate (f32 dist)
constexpr int CAP  = 96;         // logit candidate slots per row per half
constexpr int DCAP = 48;         // dist candidate slots per row per half

typedef short bf16x8 __attribute__((ext_vector_type(8)));
typedef float f32x4 __attribute__((ext_vector_type(4)));

__device__ inline unsigned short f2bf(float f) {
    unsigned x = __float_as_uint(f);
    unsigned r = x + 0x7FFFu + ((x >> 16) & 1u);   // RNE, finite inputs
    return (unsigned short)(r >> 16);
}
__device__ inline float bf2f(unsigned short h) {
    return __uint_as_float(((unsigned)h) << 16);
}
// order-preserving float <-> uint map (for LDS atomicMin/Max on floats)
__device__ inline unsigned fmap(float f) {
    unsigned b = __float_as_uint(f);
    return b ^ ((unsigned)((int)b >> 31) | 0x80000000u);
}
__device__ inline float funmap(unsigned u) {
    unsigned b = u ^ ((~(unsigned)((int)u >> 31)) | 0x80000000u);
    return __uint_as_float(b);
}
// async global->LDS DMA, 16B per lane; LDS dest = uniform base + lane*16
__device__ inline void gload16(const void* g, void* l) {
    __builtin_amdgcn_global_load_lds(
        (const __attribute__((address_space(1))) void*)g,
        (__attribute__((address_space(3))) void*)l, 16, 0, 0);
}

// ======================= FAST PATH (MFMA) =================================

// ---- prep: cb -> bf16 (RNE), norms, zero counters ------------------------
__global__ __launch_bounds__(256) void vq_prep(const float* __restrict__ x,
        const float* __restrict__ cb, unsigned short* __restrict__ ch,
        float* __restrict__ cnorm, float* __restrict__ xnorm,
        int* __restrict__ counts, int* __restrict__ dcounts) {
    int w = threadIdx.x >> 6, lane = threadIdx.x & 63;
    int gid = blockIdx.x * 256 + threadIdx.x;
    if (gid < 2 * B) { counts[gid] = 0; dcounts[gid] = 0; }
    int v = blockIdx.x * 4 + w;            // 0..16383
    if (v < N) {
        const float4* s4 = reinterpret_cast<const float4*>(cb + (size_t)v * D) + lane * 2;
        float4 a = s4[0], c = s4[1];
        float vals[8] = {a.x, a.y, a.z, a.w, c.x, c.y, c.z, c.w};
        float ns = 0.f;
        unsigned short hb[8];
        #pragma unroll
        for (int e = 0; e < 8; ++e) {
            float vv = vals[e];
            ns += vv * vv;
            hb[e] = f2bf(vv);
        }
        #pragma unroll
        for (int off = 1; off < 64; off <<= 1) ns += __shfl_xor(ns, off);
        if (lane == 0) cnorm[v] = ns;
        *reinterpret_cast<bf16x8*>(ch + (size_t)v * D + lane * 8) = *reinterpret_cast<bf16x8*>(hb);
    } else {
        int b = v - N;
        const float4* s4 = reinterpret_cast<const float4*>(x + (size_t)b * D) + lane * 2;
        float4 a = s4[0], c = s4[1];
        float ns = a.x*a.x + a.y*a.y + a.z*a.z + a.w*a.w
                 + c.x*c.x + c.y*c.y + c.z*c.z + c.w*c.w;
        #pragma unroll
        for (int off = 1; off < 64; off <<= 1) ns += __shfl_xor(ns, off);
        if (lane == 0) xnorm[b] = ns;
    }
}

// ---- LDS layout (bytes). SINGLE B tile: 64 LINEAR rows of 1024B (DMA
// dest); swizzle on SOURCE address, undone on read (rule #21). 66.5 KB
// total -> 2 blocks/CU: the co-resident block fills barrier dead time.
constexpr int OFF_B0 = 0;                  // 65536
constexpr int OFF_RM = 65536;              // 64 mapped-uint: row running max logit
constexpr int OFF_R1 = 65792;              // 64 mapped-uint: row running min dist
constexpr int OFF_CT = 66048;              // 64 int
constexpr int OFF_DC = 66304;              // 64 int
constexpr int OFF_P1 = 66560;              // 2*64 float: final merge
constexpr int OFF_P2 = 67072;
constexpr int OFF_PI = 67584;
constexpr int SMEM_BYTES = 68096;

// ---- main MFMA sweep: grid 256 = 128 row-groups x 2 N-halves ------------
// Single-buffer schedule (round-7/8-proven): GEMM(t) -> SYNC_Z -> stage(t+1)
// into same buffer -> delayed epilogue(t-1) + dsv(t) (covers DMA latency)
// -> SYNC_A drains. launch_bounds(512,4): 4 waves/EU -> 2 blocks/CU,
// VGPR cap 128 (round-12 demand = 124; WRITE_SIZE is the spill detector).
__global__ __launch_bounds__(512, 4) void vq_mfma(
        const float* __restrict__ x, const unsigned short* __restrict__ ch,
        const float* __restrict__ cnorm, const float* __restrict__ xnorm,
        const float* __restrict__ u,
        int2* __restrict__ lists, int* __restrict__ counts,
        int* __restrict__ dlists, int* __restrict__ dcounts,
        float* __restrict__ m1h, float* __restrict__ m2h, int* __restrict__ i1h) {

    __shared__ __align__(16) unsigned char smem[SMEM_BYTES];

    const int tid = threadIdx.x, w = tid >> 6, lane = tid & 63;
    const int wm = w >> 1, wn = w & 1, l15 = lane & 15, g = lane >> 4;
    const int rg = blockIdx.x >> 1, half = blockIdx.x & 1;
    const int rbase = rg * 64, nb0 = half * 4096;

    // ---- A fragments: x rows -> bf16 (RNE), single product ----
    bf16x8 ah[16];
    {
        const float* xp = x + (size_t)(rbase + wm * 16 + l15) * D + g * 8;
        #pragma unroll
        for (int ks = 0; ks < 16; ++ks) {
            const float4* p = reinterpret_cast<const float4*>(xp + ks * 32);
            float4 v0 = p[0], v1 = p[1];
            float vv[8] = {v0.x, v0.y, v0.z, v0.w, v1.x, v1.y, v1.z, v1.w};
            unsigned short hh[8];
            #pragma unroll
            for (int e = 0; e < 8; ++e) hh[e] = f2bf(vv[e]);
            ah[ks] = *reinterpret_cast<bf16x8*>(hh);
        }
    }
    float xn_r[4];
    #pragma unroll
    for (int r = 0; r < 4; ++r) xn_r[r] = xnorm[rbase + wm * 16 + g * 4 + r];

    if (tid < 64) {
        *(unsigned*)(smem + OFF_RM + tid * 4) = fmap(-INFINITY);
        *(unsigned*)(smem + OFF_R1 + tid * 4) = fmap(INFINITY);
        *(int*)(smem + OFF_CT + tid * 4) = 0;
        *(int*)(smem + OFF_DC + tid * 4) = 0;
    }

    // per-lane online state: top-2 dist + running logit max
    float d1[4], d2[4], lmax[4]; int i1[4];
    #pragma unroll
    for (int r = 0; r < 4; ++r) {
        d1[r] = INFINITY; d2[r] = INFINITY; lmax[r] = -INFINITY; i1[r] = 0;
    }

    // staging: wave w DMAs rows w*8..w*8+7; lane l reads global chunk
    // l^(row&7) so LDS chunk p holds global chunk p^(row&7).
    auto stage = [&](int nbn) {
        #pragma unroll
        for (int j = 0; j < 8; ++j) {
            const int row = w * 8 + j;
            const int c = (lane ^ j) * 8;            // j == row&7
            gload16(ch + (size_t)(nbn + row) * D + c,
                    smem + OFF_B0 + row * 1024);
        }
    };

    stage(nb0);
    __syncthreads();   // drains DMA: tile 0 resident

    const int colA = wn * 32 + l15;
    const int xr = colA & 7;
    const unsigned char* baseH = smem + OFF_B0 + colA * 1024;
    const float* ubase = u + (size_t)(rbase + wm * 16 + g * 4) * N + wn * 32 + l15;

    float dsv_prev[2][4], ur_prev[2][4];   // pipeline state (tile t-1)

    // delayed heavy epilogue (gumbel-skip fast path) for data at nbX
    auto epi_fast = [&](float (&dsvX)[2][4], float (&urX)[2][4], int nbX) {
        float rmF[4], r1F[4];
        #pragma unroll
        for (int r = 0; r < 4; ++r) {
            int rl = wm * 16 + g * 4 + r;
            rmF[r] = funmap(*(const unsigned*)(smem + OFF_RM + rl * 4));
            r1F[r] = funmap(*(const unsigned*)(smem + OFF_R1 + rl * 4));
        }
        #pragma unroll
        for (int f = 0; f < 2; ++f)
            #pragma unroll
            for (int r = 0; r < 4; ++r) {
                const int rl = wm * 16 + g * 4 + r;
                const int grow = rbase + rl;
                float ds = dsvX[f][r];
                int cidx = nbX + wn * 32 + f * 16 + l15;
                if (ds < d1[r]) { d2[r] = d1[r]; d1[r] = ds; i1[r] = cidx; }
                else if (ds < d2[r]) d2[r] = ds;
                bool need = (ds < fminf(r1F[r], d1[r]) + DELTAF)
                         || (ds < GMAX + SKIP - fmaxf(rmF[r], lmax[r]));
                if (__any(need)) {
                    float gn = -__logf(-__logf(urX[f][r] + EPSF) + EPSF);
                    float lg = gn - ds;
                    lmax[r] = fmaxf(lmax[r], lg);
                    if (ds < fminf(r1F[r], d1[r]) + DELTAF) {
                        int slot = atomicAdd((int*)(smem + OFF_DC + rl * 4), 1);
                        if (slot < DCAP) dlists[(size_t)(half * B + grow) * DCAP + slot] = cidx;
                    }
                    if (ds < r1F[r]) atomicMin((unsigned*)(smem + OFF_R1 + rl * 4), fmap(ds));
                    if (lg > fmaxf(rmF[r], lmax[r]) - SKIP) {
                        int slot = atomicAdd((int*)(smem + OFF_CT + rl * 4), 1);
                        if (slot < CAP)
                            lists[(size_t)(half * B + grow) * CAP + slot] =
                                make_int2(__float_as_int(lg), cidx);
                    }
                    if (lg > rmF[r]) atomicMax((unsigned*)(smem + OFF_RM + rl * 4), fmap(lg));
                }
            }
    };

    #pragma unroll 1
    for (int t = 0; t < 64; ++t) {
        const int nb = nb0 + t * 64;
        // u / cnorm loads for this tile (latency covered by GEMM)
        float ur[2][4];
        #pragma unroll
        for (int f = 0; f < 2; ++f)
            #pragma unroll
            for (int r = 0; r < 4; ++r)
                ur[f][r] = ubase[(size_t)r * N + f * 16 + nb];
        float cn0 = cnorm[nb + wn * 32 + l15];
        float cn1 = cnorm[nb + wn * 32 + 16 + l15];

        // GEMM: single-product bf16; 4 independent chains (ks parity x f)
        f32x4 a0e = {0.f,0.f,0.f,0.f}, a0o = {0.f,0.f,0.f,0.f};
        f32x4 a1e = {0.f,0.f,0.f,0.f}, a1o = {0.f,0.f,0.f,0.f};
        #pragma unroll
        for (int ks = 0; ks < 16; ++ks) {
            const int pos = (((ks * 4 + g) ^ xr) << 4);
            bf16x8 b0 = *reinterpret_cast<const bf16x8*>(baseH + pos);
            bf16x8 b1 = *reinterpret_cast<const bf16x8*>(baseH + 16 * 1024 + pos);
            if (ks & 1) {
                a0o = __builtin_amdgcn_mfma_f32_16x16x32_bf16(ah[ks], b0, a0o, 0, 0, 0);
                a1o = __builtin_amdgcn_mfma_f32_16x16x32_bf16(ah[ks], b1, a1o, 0, 0, 0);
            } else {
                a0e = __builtin_amdgcn_mfma_f32_16x16x32_bf16(ah[ks], b0, a0e, 0, 0, 0);
                a1e = __builtin_amdgcn_mfma_f32_16x16x32_bf16(ah[ks], b1, a1e, 0, 0, 0);
            }
        }
        __syncthreads();   // SYNC_Z: all waves done reading B(t)

        // issue DMA for tile t+1 (same buffer); latency hides under the
        // delayed epilogue + dsv work below.
        if (t < 63) stage(nb + 64);

        // delayed heavy epilogue for tile t-1 (independent of GEMM(t))
        if (t >= 2) epi_fast(dsv_prev, ur_prev, nb - 64);

        // dsv for tile t (needs this tile's acc)
        float dsv[2][4];
        #pragma unroll
        for (int f = 0; f < 2; ++f)
            #pragma unroll
            for (int r = 0; r < 4; ++r) {
                float S = f ? (a1e[r] + a1o[r]) : (a0e[r] + a0o[r]);
                dsv[f][r] = xn_r[r] - 2.f * S + (f ? cn1 : cn0);
            }

        if (t == 0) {
            // tile 0: immediate full processing, butterfly-seeded gates
            float lgv0[2][4];
            #pragma unroll
            for (int f = 0; f < 2; ++f)
                #pragma unroll
                for (int r = 0; r < 4; ++r) {
                    float ds = dsv[f][r];
                    float gn = -__logf(-__logf(ur[f][r] + EPSF) + EPSF);
                    lgv0[f][r] = gn - ds;
                    int cidx = nb + wn * 32 + f * 16 + l15;
                    if (ds < d1[r]) { d2[r] = d1[r]; d1[r] = ds; i1[r] = cidx; }
                    else if (ds < d2[r]) d2[r] = ds;
                    lmax[r] = fmaxf(lmax[r], lgv0[f][r]);
                }
            #pragma unroll
            for (int r = 0; r < 4; ++r) {
                float mx = lmax[r], mn = d1[r];
                #pragma unroll
                for (int off = 1; off < 16; off <<= 1) {
                    mx = fmaxf(mx, __shfl_xor(mx, off));
                    mn = fminf(mn, __shfl_xor(mn, off));
                }
                if (l15 == 0) {
                    int rl = wm * 16 + g * 4 + r;
                    atomicMax((unsigned*)(smem + OFF_RM + rl * 4), fmap(mx));
                    atomicMin((unsigned*)(smem + OFF_R1 + rl * 4), fmap(mn));
                }
            }
            __syncthreads();   // gates visible before tile-0 admission
            float rmF[4], r1F[4];
            #pragma unroll
            for (int r = 0; r < 4; ++r) {
                int rl = wm * 16 + g * 4 + r;
                rmF[r] = funmap(*(const unsigned*)(smem + OFF_RM + rl * 4));
                r1F[r] = funmap(*(const unsigned*)(smem + OFF_R1 + rl * 4));
            }
            #pragma unroll
            for (int f = 0; f < 2; ++f)
                #pragma unroll
                for (int r = 0; r < 4; ++r) {
                    const int rl = wm * 16 + g * 4 + r;
                    const int grow = rbase + rl;
                    float ds = dsv[f][r], lg = lgv0[f][r];
                    int cidx = nb + wn * 32 + f * 16 + l15;
                    if (ds < fminf(r1F[r], d1[r]) + DELTAF) {
                        int slot = atomicAdd((int*)(smem + OFF_DC + rl * 4), 1);
                        if (slot < DCAP) dlists[(size_t)(half * B + grow) * DCAP + slot] = cidx;
                    }
                    if (ds < r1F[r]) atomicMin((unsigned*)(smem + OFF_R1 + rl * 4), fmap(ds));
                    if (lg > fmaxf(rmF[r], lmax[r]) - SKIP) {
                        int slot = atomicAdd((int*)(smem + OFF_CT + rl * 4), 1);
                        if (slot < CAP)
                            lists[(size_t)(half * B + grow) * CAP + slot] =
                                make_int2(__float_as_int(lg), cidx);
                    }
                    if (lg > rmF[r]) atomicMax((unsigned*)(smem + OFF_RM + rl * 4), fmap(lg));
                }
        } else {
            // save pipeline state for processing at t+1
            #pragma unroll
            for (int f = 0; f < 2; ++f)
                #pragma unroll
                for (int r = 0; r < 4; ++r) {
                    dsv_prev[f][r] = dsv[f][r];
                    ur_prev[f][r] = ur[f][r];
                }
        }
        __syncthreads();   // SYNC_A: drains DMA(t+1) -> next GEMM safe
    }
    // drain pipeline: tile 63
    epi_fast(dsv_prev, ur_prev, nb0 + 63 * 64);

    // ---- final merge: butterfly over the 16 l15 lanes, then across wn ----
    #pragma unroll
    for (int r = 0; r < 4; ++r) {
        float D1 = d1[r], D2v = d2[r]; int I1 = i1[r];
        #pragma unroll
        for (int off = 1; off < 16; off <<= 1) {
            float o1 = __shfl_xor(D1, off), o2 = __shfl_xor(D2v, off);
            int oi = __shfl_xor(I1, off);
            if (o1 < D1 || (o1 == D1 && oi < I1)) { D2v = fminf(D1, o2); D1 = o1; I1 = oi; }
            else D2v = fminf(o1, D2v);
        }
        if (l15 == 0) {
            int rl = wm * 16 + g * 4 + r;
            *(float*)(smem + OFF_P1 + (wn * 64 + rl) * 4) = D1;
            *(float*)(smem + OFF_P2 + (wn * 64 + rl) * 4) = D2v;
            *(int*)(smem + OFF_PI + (wn * 64 + rl) * 4) = I1;
        }
    }
    __syncthreads();
    if (tid < 64) {
        float a1 = *(float*)(smem + OFF_P1 + tid * 4), a2 = *(float*)(smem + OFF_P2 + tid * 4);
        int ai = *(int*)(smem + OFF_PI + tid * 4);
        float b1 = *(float*)(smem + OFF_P1 + (64 + tid) * 4), b2 = *(float*)(smem + OFF_P2 + (64 + tid) * 4);
        int bi = *(int*)(smem + OFF_PI + (64 + tid) * 4);
        float m1, m2; int mi;
        if (b1 < a1 || (b1 == a1 && bi < ai)) { m1 = b1; mi = bi; m2 = fminf(a1, b2); }
        else                                  { m1 = a1; mi = ai; m2 = fminf(b1, a2); }
        int hrow = half * B + rbase + tid;
        m1h[hrow] = m1; m2h[hrow] = m2; i1h[hrow] = mi;
        counts[hrow] = *(int*)(smem + OFF_CT + tid * 4);    // RAW (overflow detect)
        dcounts[hrow] = *(int*)(smem + OFF_DC + tid * 4);   // RAW (overflow detect)
    }
}

// ---- finalize: softmax over candidate lists -> quantized, loss; merge top2
__global__ __launch_bounds__(256) void vq_finalize(
        const float* __restrict__ cb, const float* __restrict__ x,
        const int2* __restrict__ lists, const int* __restrict__ counts,
        float* __restrict__ m1h, float* __restrict__ m2h, int* __restrict__ i1h,
        float* __restrict__ out_q, float* __restrict__ out_loss) {
    __shared__ int2 ebuf[4][2 * CAP];
    int w = threadIdx.x >> 6, lane = threadIdx.x & 63;
    int row = blockIdx.x * 4 + w;
    int n0 = counts[row];      if (n0 > CAP) n0 = CAP;
    int n1 = counts[B + row];  if (n1 > CAP) n1 = CAP;
    int n = n0 + n1;
    for (int e = lane; e < n0; e += 64) ebuf[w][e] = lists[(size_t)row * CAP + e];
    for (int e = lane; e < n1; e += 64) ebuf[w][n0 + e] = lists[(size_t)(B + row) * CAP + e];
    __syncthreads();
    float m = -INFINITY;
    for (int e = lane; e < n; e += 64) m = fmaxf(m, __int_as_float(ebuf[w][e].x));
    #pragma unroll
    for (int off = 1; off < 64; off <<= 1) m = fmaxf(m, __shfl_xor(m, off));
    float denom = 0.f;
    for (int e = lane; e < n; e += 64) denom += __expf(__int_as_float(ebuf[w][e].x) - m);
    #pragma unroll
    for (int off = 1; off < 64; off <<= 1) denom += __shfl_xor(denom, off);
    float q[8] = {0.f, 0.f, 0.f, 0.f, 0.f, 0.f, 0.f, 0.f};
    for (int e = 0; e < n; ++e) {
        int2 ent = ebuf[w][e];
        float wgt = __expf(__int_as_float(ent.x) - m);
        if (wgt < 1e-9f) continue;   // negligible entry: skip codebook read
        const float4* c4 = reinterpret_cast<const float4*>(cb + (size_t)ent.y * D + lane * 8);
        float4 c0 = c4[0], c1 = c4[1];
        q[0] += wgt * c0.x; q[1] += wgt * c0.y; q[2] += wgt * c0.z; q[3] += wgt * c0.w;
        q[4] += wgt * c1.x; q[5] += wgt * c1.y; q[6] += wgt * c1.z; q[7] += wgt * c1.w;
    }
    float inv = 1.f / denom;
    const float4* x4 = reinterpret_cast<const float4*>(x + (size_t)row * D + lane * 8);
    float4 xa = x4[0], xb = x4[1];
    float xs[8] = {xa.x, xa.y, xa.z, xa.w, xb.x, xb.y, xb.z, xb.w};
    float ls = 0.f;
    #pragma unroll
    for (int k = 0; k < 8; ++k) {
        q[k] *= inv;
        float dlt = xs[k] - q[k];
        ls += dlt * dlt;
    }
    float4 q0 = {q[0], q[1], q[2], q[3]}, q1 = {q[4], q[5], q[6], q[7]};
    float4* o = reinterpret_cast<float4*>(out_q + (size_t)row * D + lane * 8);
    o[0] = q0; o[1] = q1;
    #pragma unroll
    for (int off = 1; off < 64; off <<= 1) ls += __shfl_xor(ls, off);
    if (lane == 0) {
        out_loss[row] = 1.25f * ls;
        float a1 = m1h[row], a2 = m2h[row]; int ai = i1h[row];
        float b1 = m1h[B + row], b2 = m2h[B + row]; int bi = i1h[B + row];
        float mm1, mm2; int mi;
        if (b1 < a1 || (b1 == a1 && bi < ai)) { mm1 = b1; mi = bi; mm2 = fminf(a1, b2); }
        else                                  { mm1 = a1; mi = ai; mm2 = fminf(b1, a2); }
        m1h[row] = mm1; m2h[row] = mm2; i1h[row] = mi;
    }
}

// ---- full-row softmax fallback for logit-list overflow (expected: 0 rows)
__global__ __launch_bounds__(256) void vq_row_full(
        const float* __restrict__ x, const float* __restrict__ cb,
        const float* __restrict__ cnorm, const float* __restrict__ u,
        const int* __restrict__ counts,
        float* __restrict__ out_q, float* __restrict__ out_loss) {
    int row = blockIdx.x;
    if (counts[row] <= CAP && counts[B + row] <= CAP) return;
    int tid = threadIdx.x, wv_ = tid >> 6, lane = tid & 63;
    __shared__ float xs[D];
    __shared__ float red[4];
    __shared__ float wts[256]; __shared__ int ids[256]; __shared__ int nc;
    for (int i = tid; i < D; i += 256) xs[i] = x[(size_t)row * D + i];
    if (tid == 0) nc = 0;
    __syncthreads();
    float xn = 0.f;
    for (int i = tid; i < D; i += 256) xn += xs[i] * xs[i];
    #pragma unroll
    for (int off = 1; off < 64; off <<= 1) xn += __shfl_xor(xn, off);
    if (lane == 0) red[wv_] = xn;
    __syncthreads();
    xn = red[0] + red[1] + red[2] + red[3];
    __syncthreads();
    float m = -INFINITY;
    for (int n = tid; n < N; n += 256) {
        float dot = 0.f;
        const float* c = cb + (size_t)n * D;
        for (int d = 0; d < D; ++d) dot = fmaf(xs[d], c[d], dot);
        float lg = -__logf(-__logf(u[(size_t)row * N + n] + EPSF) + EPSF)
                 - (xn - 2.f * dot + cnorm[n]);
        m = fmaxf(m, lg);
    }
    #pragma unroll
    for (int off = 1; off < 64; off <<= 1) m = fmaxf(m, __shfl_xor(m, off));
    if (lane == 0) red[wv_] = m;
    __syncthreads();
    m = fmaxf(fmaxf(red[0], red[1]), fmaxf(red[2], red[3]));
    __syncthreads();
    float denom = 0.f;
    for (int n = tid; n < N; n += 256) {
        float dot = 0.f;
        const float* c = cb + (size_t)n * D;
        for (int d = 0; d < D; ++d) dot = fmaf(xs[d], c[d], dot);
        float lg = -__logf(-__logf(u[(size_t)row * N + n] + EPSF) + EPSF)
                 - (xn - 2.f * dot + cnorm[n]);
        float wv2 = __expf(lg - m);
        denom += wv2;
        if (wv2 > 1e-8f) {
            int s = atomicAdd(&nc, 1);
            if (s < 256) { wts[s] = wv2; ids[s] = n; }
        }
    }
    #pragma unroll
    for (int off = 1; off < 64; off <<= 1) denom += __shfl_xor(denom, off);
    if (lane == 0) red[wv_] = denom;
    __syncthreads();
    denom = red[0] + red[1] + red[2] + red[3];
    int ncl = nc < 256 ? nc : 256;
    float q0 = 0.f, q1 = 0.f;
    for (int e = 0; e < ncl; ++e) {
        const float* c = cb + (size_t)ids[e] * D;
        q0 += wts[e] * c[tid * 2];
        q1 += wts[e] * c[tid * 2 + 1];
    }
    q0 /= denom; q1 /= denom;
    out_q[(size_t)row * D + tid * 2] = q0;
    out_q[(size_t)row * D + tid * 2 + 1] = q1;
    float dl0 = xs[tid * 2] - q0, dl1 = xs[tid * 2 + 1] - q1;
    float ls = dl0 * dl0 + dl1 * dl1;
    #pragma unroll
    for (int off = 1; off < 64; off <<= 1) ls += __shfl_xor(ls, off);
    __syncthreads();
    if (lane == 0) red[wv_] = ls;
    __syncthreads();
    if (tid == 0) out_loss[row] = 1.25f * (red[0] + red[1] + red[2] + red[3]);
}

// ---- candidate-based f64 argmin recheck (one wave per row) --------------
__global__ __launch_bounds__(256) void argmin_fix2(
        const float* __restrict__ x, const float* __restrict__ cb,
        const float* __restrict__ m1h, const float* __restrict__ m2h,
        const int* __restrict__ i1h,
        const int* __restrict__ dcounts, const int* __restrict__ dlists,
        float* __restrict__ out_ind) {
    int w = threadIdx.x >> 6, lane = threadIdx.x & 63;
    int row = blockIdx.x * 4 + w;
    if (m2h[row] - m1h[row] >= DELTAF) {
        if (lane == 0) out_ind[row] = (float)i1h[row];
        return;
    }
    const float4* x4 = reinterpret_cast<const float4*>(x + (size_t)row * D) + lane * 2;
    float4 xa = x4[0], xb = x4[1];
    double xd[8] = {(double)xa.x, (double)xa.y, (double)xa.z, (double)xa.w,
                    (double)xb.x, (double)xb.y, (double)xb.z, (double)xb.w};
    double bestv = 1e300; int besti = 0x7fffffff;

    auto evalCode = [&](int n) {
        const float4* c4 = reinterpret_cast<const float4*>(cb + (size_t)n * D) + lane * 2;
        float4 ca = c4[0], cbv = c4[1];
        double cd[8] = {(double)ca.x, (double)ca.y, (double)ca.z, (double)ca.w,
                        (double)cbv.x, (double)cbv.y, (double)cbv.z, (double)cbv.w};
        double s = 0.0;
        #pragma unroll
        for (int k = 0; k < 8; ++k) {
            double dlt = xd[k] - cd[k];
            s = fma(dlt, dlt, s);
        }
        #pragma unroll
        for (int off = 1; off < 64; off <<= 1) s += __shfl_xor(s, off);
        if (s < bestv || (s == bestv && n < besti)) { bestv = s; besti = n; }
    };

    int n0 = dcounts[row], n1 = dcounts[B + row];
    if (n0 <= DCAP && n1 <= DCAP) {
        evalCode(i1h[row]);   // hardening: never worse than the bf16 argmin
        for (int e = 0; e < n0; ++e) evalCode(dlists[(size_t)row * DCAP + e]);
        for (int e = 0; e < n1; ++e) evalCode(dlists[(size_t)(B + row) * DCAP + e]);
    } else {
        for (int n = 0; n < N; ++n) evalCode(n);   // rare overflow fallback
    }
    if (lane == 0) out_ind[row] = (float)besti;
}

// ======================= FALLBACK PATH (round-1, passing) =================
constexpr int ROWS = 16;
constexpr int NT   = 256;
constexpr int DT   = 16;

__global__ __launch_bounds__(256) void prep_norms(const float* __restrict__ x,
                                                  const float* __restrict__ cb,
                                                  float* __restrict__ cnorm,
                                                  float* __restrict__ xnorm) {
    int wave = threadIdx.x >> 6, lane = threadIdx.x & 63;
    int v = blockIdx.x * 4 + wave;
    const float* src;
    float* dst;
    if (v < N) { src = cb + (size_t)v * D; dst = cnorm + v; }
    else       { int b = v - N; if (b >= B) return; src = x + (size_t)b * D; dst = xnorm + b; }
    const float4* s4 = reinterpret_cast<const float4*>(src) + lane * 2;
    float4 a = s4[0], c = s4[1];
    float s = a.x*a.x + a.y*a.y + a.z*a.z + a.w*a.w
            + c.x*c.x + c.y*c.y + c.z*c.z + c.w*c.w;
    #pragma unroll
    for (int off = 1; off < 64; off <<= 1) s += __shfl_xor(s, off);
    if (lane == 0) *dst = s;
}

__global__ __launch_bounds__(256) void vq_main(const float* __restrict__ x,
        const float* __restrict__ cb, const float* __restrict__ u,
        const float* __restrict__ cnorm, const float* __restrict__ xnorm,
        float* __restrict__ out_q, float* __restrict__ out_loss,
        float* __restrict__ m1w, float* __restrict__ m2w, int* __restrict__ i1w) {

    __shared__ float xs[ROWS][D];
    __shared__ float ct[DT][NT];

    const int tid  = threadIdx.x;
    const int wave = tid >> 6, lane = tid & 63;
    const int rbase = blockIdx.x * ROWS;
    const int wrow  = rbase + wave * 4;

    for (int i = tid; i < ROWS * (D / 4); i += 256)
        reinterpret_cast<float4*>(xs)[i] =
            reinterpret_cast<const float4*>(x + (size_t)rbase * D)[i];
    __syncthreads();

    float xn[4];
    #pragma unroll
    for (int r = 0; r < 4; ++r) xn[r] = xnorm[wrow + r];

    float m[4], denom[4], acc[4][8];
    float am1[4], am2[4]; int ai1[4];
    #pragma unroll
    for (int r = 0; r < 4; ++r) {
        m[r] = -INFINITY; denom[r] = 0.f;
        am1[r] = INFINITY; am2[r] = INFINITY; ai1[r] = 0;
        #pragma unroll
        for (int k = 0; k < 8; ++k) acc[r][k] = 0.f;
    }

    for (int nb = 0; nb < N; nb += NT) {
        float S[4][4];
        #pragma unroll
        for (int r = 0; r < 4; ++r)
            #pragma unroll
            for (int j = 0; j < 4; ++j) S[r][j] = 0.f;

        for (int db = 0; db < D; db += DT) {
            __syncthreads();
            {
                const float4* src = reinterpret_cast<const float4*>(
                        cb + (size_t)(nb + tid) * D + db);
                float4 a0 = src[0], a1 = src[1], a2 = src[2], a3 = src[3];
                ct[ 0][tid]=a0.x; ct[ 1][tid]=a0.y; ct[ 2][tid]=a0.z; ct[ 3][tid]=a0.w;
                ct[ 4][tid]=a1.x; ct[ 5][tid]=a1.y; ct[ 6][tid]=a1.z; ct[ 7][tid]=a1.w;
                ct[ 8][tid]=a2.x; ct[ 9][tid]=a2.y; ct[10][tid]=a2.z; ct[11][tid]=a2.w;
                ct[12][tid]=a3.x; ct[13][tid]=a3.y; ct[14][tid]=a3.z; ct[15][tid]=a3.w;
            }
            __syncthreads();
            #pragma unroll
            for (int dq = 0; dq < DT / 4; ++dq) {
                float creg[4][4];
                #pragma unroll
                for (int k = 0; k < 4; ++k) {
                    float4 cv = *reinterpret_cast<const float4*>(&ct[dq*4 + k][4*lane]);
                    creg[k][0]=cv.x; creg[k][1]=cv.y; creg[k][2]=cv.z; creg[k][3]=cv.w;
                }
                #pragma unroll
                for (int r = 0; r < 4; ++r) {
                    float4 xv = *reinterpret_cast<const float4*>(&xs[wave*4 + r][db + dq*4]);
                    float xr[4] = {xv.x, xv.y, xv.z, xv.w};
                    #pragma unroll
                    for (int k = 0; k < 4; ++k)
                        #pragma unroll
                        for (int j = 0; j < 4; ++j)
                            S[r][j] = fmaf(xr[k], creg[k][j], S[r][j]);
                }
            }
        }

        float4 cn4 = *reinterpret_cast<const float4*>(&cnorm[nb + 4*lane]);
        float cn[4] = {cn4.x, cn4.y, cn4.z, cn4.w};

        float logit[4][4], dist[4][4];
        #pragma unroll
        for (int r = 0; r < 4; ++r) {
            float4 u4 = *reinterpret_cast<const float4*>(
                    &u[(size_t)(wrow + r) * N + nb + 4*lane]);
            float uu[4] = {u4.x, u4.y, u4.z, u4.w};
            #pragma unroll
            for (int j = 0; j < 4; ++j) {
                float ds = xn[r] - 2.f * S[r][j] + cn[j];
                float gg  = -logf(-logf(uu[j] + EPSF) + EPSF);
                dist[r][j]  = ds;
                logit[r][j] = gg - ds;
            }
        }

        #pragma unroll
        for (int r = 0; r < 4; ++r) {
            float l1 = INFINITY, l2 = INFINITY; int li = 0;
            #pragma unroll
            for (int j = 0; j < 4; ++j) {
                float dv = dist[r][j]; int idx = nb + 4*lane + j;
                if (dv < l1)      { l2 = l1; l1 = dv; li = idx; }
                else if (dv < l2) { l2 = dv; }
            }
            #pragma unroll
            for (int off = 1; off < 64; off <<= 1) {
                float o1 = __shfl_xor(l1, off), o2 = __shfl_xor(l2, off);
                int   oi = __shfl_xor(li, off);
                if (o1 < l1 || (o1 == l1 && oi < li)) { l2 = fminf(l1, o2); l1 = o1; li = oi; }
                else                                  { l2 = fminf(o1, l2); }
            }
            if (l1 < am1[r] || (l1 == am1[r] && li < ai1[r])) {
                am2[r] = fminf(am1[r], l2); am1[r] = l1; ai1[r] = li;
            } else {
                am2[r] = fminf(am2[r], l1);
            }

            float lm = fmaxf(fmaxf(logit[r][0], logit[r][1]),
                             fmaxf(logit[r][2], logit[r][3]));
            #pragma unroll
            for (int off = 1; off < 64; off <<= 1) lm = fmaxf(lm, __shfl_xor(lm, off));
            if (lm > m[r]) {
                float s = expf(m[r] - lm);
                denom[r] *= s;
                #pragma unroll
                for (int k = 0; k < 8; ++k) acc[r][k] *= s;
                m[r] = lm;
            }

            float wv[4];
            #pragma unroll
            for (int j = 0; j < 4; ++j) {
                float e = logit[r][j] - m[r];
                bool act = e > -SKIP;
                wv[j] = act ? expf(e) : 0.f;
                denom[r] += wv[j];
            }
            #pragma unroll
            for (int j = 0; j < 4; ++j) {
                unsigned long long mk = __ballot(wv[j] > 0.f);
                while (mk) {
                    int L = __ffsll((unsigned long long)mk) - 1;
                    mk &= mk - 1;
                    float wb = __shfl(wv[j], L);
                    int nstar = nb + 4*L + j;
                    const float4* crow = reinterpret_cast<const float4*>(
                            cb + (size_t)nstar * D + 8*lane);
                    float4 c0 = crow[0], c1 = crow[1];
                    acc[r][0] = fmaf(wb, c0.x, acc[r][0]);
                    acc[r][1] = fmaf(wb, c0.y, acc[r][1]);
                    acc[r][2] = fmaf(wb, c0.z, acc[r][2]);
                    acc[r][3] = fmaf(wb, c0.w, acc[r][3]);
                    acc[r][4] = fmaf(wb, c1.x, acc[r][4]);
                    acc[r][5] = fmaf(wb, c1.y, acc[r][5]);
                    acc[r][6] = fmaf(wb, c1.z, acc[r][6]);
                    acc[r][7] = fmaf(wb, c1.w, acc[r][7]);
                }
            }
        }
    }

    #pragma unroll
    for (int r = 0; r < 4; ++r) {
        float dn = denom[r];
        #pragma unroll
        for (int off = 1; off < 64; off <<= 1) dn += __shfl_xor(dn, off);
        float inv = 1.f / dn;
        int row = wrow + r;
        float q[8]; float ls = 0.f;
        #pragma unroll
        for (int k = 0; k < 8; ++k) {
            q[k] = acc[r][k] * inv;
            float dlt = xs[wave*4 + r][8*lane + k] - q[k];
            ls += dlt * dlt;
        }
        float4 q0 = {q[0], q[1], q[2], q[3]}, q1 = {q[4], q[5], q[6], q[7]};
        float4* o = reinterpret_cast<float4*>(out_q + (size_t)row * D + 8*lane);
        o[0] = q0; o[1] = q1;
        #pragma unroll
        for (int off = 1; off < 64; off <<= 1) ls += __shfl_xor(ls, off);
        if (lane == 0) {
            out_loss[row] = 1.25f * ls;
            m1w[row] = am1[r]; m2w[row] = am2[r]; i1w[row] = ai1[r];
        }
    }
}

// ---- full-scan f64 argmin recheck (fallback path only) -------------------
__global__ __launch_bounds__(256) void argmin_fix(const float* __restrict__ x,
        const float* __restrict__ cb, const float* __restrict__ m1w,
        const float* __restrict__ m2w, const int* __restrict__ i1w,
        float* __restrict__ out_ind) {
    int b = blockIdx.x, tid = threadIdx.x;
    if (m2w[b] - m1w[b] >= DELTA) {
        if (tid == 0) out_ind[b] = (float)i1w[b];
        return;
    }
    __shared__ double xsd[D];
    for (int i = tid; i < D; i += 256) xsd[i] = (double)x[(size_t)b * D + i];
    __syncthreads();
    double xn = 0.0;
    for (int d = 0; d < D; ++d) xn += xsd[d] * xsd[d];

    double bestv = 1e300; int besti = N;
    for (int n = tid; n < N; n += 256) {
        const float* c = cb + (size_t)n * D;
        double d0 = 0.0, d1v = 0.0, c0 = 0.0, c1v = 0.0;
        for (int d = 0; d < D; d += 2) {
            double ca = (double)c[d], cbv = (double)c[d + 1];
            d0 += xsd[d] * ca;  c0 += ca * ca;
            d1v += xsd[d + 1] * cbv; c1v += cbv * cbv;
        }
        double dv = xn - 2.0 * (d0 + d1v) + (c0 + c1v);
        if (dv < bestv || (dv == bestv && n < besti)) { bestv = dv; besti = n; }
    }
    __shared__ double rv[256]; __shared__ int ri[256];
    rv[tid] = bestv; ri[tid] = besti;
    __syncthreads();
    for (int s = 128; s > 0; s >>= 1) {
        if (tid < s) {
            if (rv[tid+s] < rv[tid] || (rv[tid+s] == rv[tid] && ri[tid+s] < ri[tid])) {
                rv[tid] = rv[tid+s]; ri[tid] = ri[tid+s];
            }
        }
        __syncthreads();
    }
    if (tid == 0) out_ind[b] = (float)ri[0];
}

// ---------------- host launch --------------------------------------------
extern "C" void kernel_launch(void* const* d_in, const int* in_sizes, int n_in,
                              void* d_out, int out_size, void* d_ws, size_t ws_size,
                              hipStream_t stream) {
    const float* x  = (const float*)d_in[0];
    const float* cb = (const float*)d_in[1];
    const float* u  = (const float*)d_in[2];
    float* out      = (float*)d_out;
    float* out_q    = out;
    float* out_ind  = out + (size_t)B * D;
    float* out_loss = out_ind + B;

    // fast-path workspace layout (bytes)
    const size_t O_CH = 0;
    const size_t O_CN = O_CH + (size_t)N * D * 2;          // 8 MB
    const size_t O_XN = O_CN + (size_t)N * 4;
    const size_t O_M1 = O_XN + (size_t)B * 4;
    const size_t O_M2 = O_M1 + (size_t)2 * B * 4;
    const size_t O_I1 = O_M2 + (size_t)2 * B * 4;
    const size_t O_CT = O_I1 + (size_t)2 * B * 4;
    const size_t O_DC = O_CT + (size_t)2 * B * 4;
    const size_t O_LS = O_DC + (size_t)2 * B * 4;
    const size_t O_DL = O_LS + (size_t)2 * B * CAP * 8;    // 12.6 MB
    const size_t NEED = O_DL + (size_t)2 * B * DCAP * 4;   // ~24.5 MB

    if (ws_size >= NEED) {
        char* w8 = (char*)d_ws;
        unsigned short* ch = (unsigned short*)(w8 + O_CH);
        float* cnorm = (float*)(w8 + O_CN);
        float* xnorm = (float*)(w8 + O_XN);
        float* m1h   = (float*)(w8 + O_M1);
        float* m2h   = (float*)(w8 + O_M2);
        int*   i1h   = (int*)(w8 + O_I1);
        int*   counts= (int*)(w8 + O_CT);
        int*   dcounts=(int*)(w8 + O_DC);
        int2*  lists = (int2*)(w8 + O_LS);
        int*   dlists= (int*)(w8 + O_DL);

        hipLaunchKernelGGL(vq_prep, dim3((N + B) / 4), dim3(256), 0, stream,
                           x, cb, ch, cnorm, xnorm, counts, dcounts);
        hipLaunchKernelGGL(vq_mfma, dim3(256), dim3(512), 0, stream,
                           x, ch, cnorm, xnorm, u, lists, counts,
                           dlists, dcounts, m1h, m2h, i1h);
        hipLaunchKernelGGL(vq_finalize, dim3(B / 4), dim3(256), 0, stream,
                           cb, x, lists, counts, m1h, m2h, i1h, out_q, out_loss);
        hipLaunchKernelGGL(vq_row_full, dim3(B), dim3(256), 0, stream,
                           x, cb, cnorm, u, counts, out_q, out_loss);
        hipLaunchKernelGGL(argmin_fix2, dim3(B / 4), dim3(256), 0, stream,
                           x, cb, m1h, m2h, i1h, dcounts, dlists, out_ind);
    } else {
        float* ws    = (float*)d_ws;
        float* cnorm = ws;
        float* xnorm = ws + N;
        float* m1w   = xnorm + B;
        float* m2w   = m1w + B;
        int*   i1w   = (int*)(m2w + B);

        hipLaunchKernelGGL(prep_norms, dim3((N + B) / 4), dim3(256), 0, stream,
                           x, cb, cnorm, xnorm);
        hipLaunchKernelGGL(vq_main, dim3(B / ROWS), dim3(256), 0, stream,
                           x, cb, u, cnorm, xnorm, out_q, out_loss, m1w, m2w, i1w);
        hipLaunchKernelGGL(argmin_fix, dim3(B), dim3(256), 0, stream,
                           x, cb, m1w, m2w, i1w, out_ind);
    }
}

// Round 14
// 285.266 us; speedup vs baseline: 3.3818x; 3.3818x over previous
//
#include <hip/hip_runtime.h>
#include <math.h>

// VectorQuantization: B=8192 rows, N=8192 codes, D=512
// out = [quantized (B*D) | ind (B, as float) | loss (B)]
constexpr int B = 8192, N = 8192, D = 512;
constexpr float EPSF = 1e-20f;
constexpr float SKIP   = 20.0f;  // exp(-20) ~ 2e-9: safely negligible
constexpr float GMAX   = 17.0f;  // -log(-log(u+eps)) <= 16.7 for fp32 u in [0,1)
constexpr float DELTAF = 1.0f;   // single-product bf16 dist gate (~14 sigma)
constexpr float DELTA  = 0.05f;  // fallback-path dist gate (f32 dist)
constexpr int CAP  = 96;         // logit candidate slots per row per half
constexpr int DCAP = 48;         // dist candidate slots per row per half

typedef short bf16x8 __attribute__((ext_vector_type(8)));
typedef float f32x4 __attribute__((ext_vector_type(4)));

__device__ inline unsigned short f2bf(float f) {
    unsigned x = __float_as_uint(f);
    unsigned r = x + 0x7FFFu + ((x >> 16) & 1u);   // RNE, finite inputs
    return (unsigned short)(r >> 16);
}
__device__ inline float bf2f(unsigned short h) {
    return __uint_as_float(((unsigned)h) << 16);
}
// order-preserving float <-> uint map (for LDS atomicMin/Max on floats)
__device__ inline unsigned fmap(float f) {
    unsigned b = __float_as_uint(f);
    return b ^ ((unsigned)((int)b >> 31) | 0x80000000u);
}
__device__ inline float funmap(unsigned u) {
    unsigned b = u ^ ((~(unsigned)((int)u >> 31)) | 0x80000000u);
    return __uint_as_float(b);
}
// async global->LDS DMA, 16B per lane; LDS dest = uniform base + lane*16
__device__ inline void gload16(const void* g, void* l) {
    __builtin_amdgcn_global_load_lds(
        (const __attribute__((address_space(1))) void*)g,
        (__attribute__((address_space(3))) void*)l, 16, 0, 0);
}

// ======================= FAST PATH (MFMA) =================================

// ---- prep: cb -> bf16 (RNE), norms, zero counters ------------------------
__global__ __launch_bounds__(256) void vq_prep(const float* __restrict__ x,
        const float* __restrict__ cb, unsigned short* __restrict__ ch,
        float* __restrict__ cnorm, float* __restrict__ xnorm,
        int* __restrict__ counts, int* __restrict__ dcounts) {
    int w = threadIdx.x >> 6, lane = threadIdx.x & 63;
    int gid = blockIdx.x * 256 + threadIdx.x;
    if (gid < 2 * B) { counts[gid] = 0; dcounts[gid] = 0; }
    int v = blockIdx.x * 4 + w;            // 0..16383
    if (v < N) {
        const float4* s4 = reinterpret_cast<const float4*>(cb + (size_t)v * D) + lane * 2;
        float4 a = s4[0], c = s4[1];
        float vals[8] = {a.x, a.y, a.z, a.w, c.x, c.y, c.z, c.w};
        float ns = 0.f;
        unsigned short hb[8];
        #pragma unroll
        for (int e = 0; e < 8; ++e) {
            float vv = vals[e];
            ns += vv * vv;
            hb[e] = f2bf(vv);
        }
        #pragma unroll
        for (int off = 1; off < 64; off <<= 1) ns += __shfl_xor(ns, off);
        if (lane == 0) cnorm[v] = ns;
        *reinterpret_cast<bf16x8*>(ch + (size_t)v * D + lane * 8) = *reinterpret_cast<bf16x8*>(hb);
    } else {
        int b = v - N;
        const float4* s4 = reinterpret_cast<const float4*>(x + (size_t)b * D) + lane * 2;
        float4 a = s4[0], c = s4[1];
        float ns = a.x*a.x + a.y*a.y + a.z*a.z + a.w*a.w
                 + c.x*c.x + c.y*c.y + c.z*c.z + c.w*c.w;
        #pragma unroll
        for (int off = 1; off < 64; off <<= 1) ns += __shfl_xor(ns, off);
        if (lane == 0) xnorm[b] = ns;
    }
}

// ---- LDS layout (bytes). SINGLE B tile: 64 LINEAR rows of 1024B (DMA
// dest); swizzle on SOURCE address, undone on read (rule #21). 66.5 KB
// total -> 2 blocks/CU: the co-resident block fills barrier dead time.
constexpr int OFF_B0 = 0;                  // 65536
constexpr int OFF_RM = 65536;              // 64 mapped-uint: row running max logit
constexpr int OFF_R1 = 65792;              // 64 mapped-uint: row running min dist
constexpr int OFF_CT = 66048;              // 64 int
constexpr int OFF_DC = 66304;              // 64 int
constexpr int OFF_P1 = 66560;              // 2*64 float: final merge
constexpr int OFF_P2 = 67072;
constexpr int OFF_PI = 67584;
constexpr int SMEM_BYTES = 68096;

// ---- main MFMA sweep: grid 256 = 128 row-groups x 2 N-halves ------------
// Single-buffer schedule (round-7/8-proven): GEMM(t) -> SYNC_Z -> stage(t+1)
// into same buffer -> delayed epilogue(t-1) + dsv(t) (covers DMA latency)
// -> SYNC_A drains.
// __launch_bounds__ 2nd arg = min BLOCKS/CU (evidence: (512,2)->cap128 r5,
// (512,1)->cap256 r6-12, (512,4)->cap64+spill r13). We want 2 blocks/CU:
// (512,2) -> 16 waves/CU -> VGPR cap 128 >= demand ~124. Spill detector:
// WRITE_SIZE.
__global__ __launch_bounds__(512, 2) void vq_mfma(
        const float* __restrict__ x, const unsigned short* __restrict__ ch,
        const float* __restrict__ cnorm, const float* __restrict__ xnorm,
        const float* __restrict__ u,
        int2* __restrict__ lists, int* __restrict__ counts,
        int* __restrict__ dlists, int* __restrict__ dcounts,
        float* __restrict__ m1h, float* __restrict__ m2h, int* __restrict__ i1h) {

    __shared__ __align__(16) unsigned char smem[SMEM_BYTES];

    const int tid = threadIdx.x, w = tid >> 6, lane = tid & 63;
    const int wm = w >> 1, wn = w & 1, l15 = lane & 15, g = lane >> 4;
    const int rg = blockIdx.x >> 1, half = blockIdx.x & 1;
    const int rbase = rg * 64, nb0 = half * 4096;

    // ---- A fragments: x rows -> bf16 (RNE), single product ----
    bf16x8 ah[16];
    {
        const float* xp = x + (size_t)(rbase + wm * 16 + l15) * D + g * 8;
        #pragma unroll
        for (int ks = 0; ks < 16; ++ks) {
            const float4* p = reinterpret_cast<const float4*>(xp + ks * 32);
            float4 v0 = p[0], v1 = p[1];
            float vv[8] = {v0.x, v0.y, v0.z, v0.w, v1.x, v1.y, v1.z, v1.w};
            unsigned short hh[8];
            #pragma unroll
            for (int e = 0; e < 8; ++e) hh[e] = f2bf(vv[e]);
            ah[ks] = *reinterpret_cast<bf16x8*>(hh);
        }
    }
    float xn_r[4];
    #pragma unroll
    for (int r = 0; r < 4; ++r) xn_r[r] = xnorm[rbase + wm * 16 + g * 4 + r];

    if (tid < 64) {
        *(unsigned*)(smem + OFF_RM + tid * 4) = fmap(-INFINITY);
        *(unsigned*)(smem + OFF_R1 + tid * 4) = fmap(INFINITY);
        *(int*)(smem + OFF_CT + tid * 4) = 0;
        *(int*)(smem + OFF_DC + tid * 4) = 0;
    }

    // per-lane online state: top-2 dist + running logit max
    float d1[4], d2[4], lmax[4]; int i1[4];
    #pragma unroll
    for (int r = 0; r < 4; ++r) {
        d1[r] = INFINITY; d2[r] = INFINITY; lmax[r] = -INFINITY; i1[r] = 0;
    }

    // staging: wave w DMAs rows w*8..w*8+7; lane l reads global chunk
    // l^(row&7) so LDS chunk p holds global chunk p^(row&7).
    auto stage = [&](int nbn) {
        #pragma unroll
        for (int j = 0; j < 8; ++j) {
            const int row = w * 8 + j;
            const int c = (lane ^ j) * 8;            // j == row&7
            gload16(ch + (size_t)(nbn + row) * D + c,
                    smem + OFF_B0 + row * 1024);
        }
    };

    stage(nb0);
    __syncthreads();   // drains DMA: tile 0 resident

    const int colA = wn * 32 + l15;
    const int xr = colA & 7;
    const unsigned char* baseH = smem + OFF_B0 + colA * 1024;
    const float* ubase = u + (size_t)(rbase + wm * 16 + g * 4) * N + wn * 32 + l15;

    float dsv_prev[2][4], ur_prev[2][4];   // pipeline state (tile t-1)

    // delayed heavy epilogue (gumbel-skip fast path) for data at nbX
    auto epi_fast = [&](float (&dsvX)[2][4], float (&urX)[2][4], int nbX) {
        float rmF[4], r1F[4];
        #pragma unroll
        for (int r = 0; r < 4; ++r) {
            int rl = wm * 16 + g * 4 + r;
            rmF[r] = funmap(*(const unsigned*)(smem + OFF_RM + rl * 4));
            r1F[r] = funmap(*(const unsigned*)(smem + OFF_R1 + rl * 4));
        }
        #pragma unroll
        for (int f = 0; f < 2; ++f)
            #pragma unroll
            for (int r = 0; r < 4; ++r) {
                const int rl = wm * 16 + g * 4 + r;
                const int grow = rbase + rl;
                float ds = dsvX[f][r];
                int cidx = nbX + wn * 32 + f * 16 + l15;
                if (ds < d1[r]) { d2[r] = d1[r]; d1[r] = ds; i1[r] = cidx; }
                else if (ds < d2[r]) d2[r] = ds;
                bool need = (ds < fminf(r1F[r], d1[r]) + DELTAF)
                         || (ds < GMAX + SKIP - fmaxf(rmF[r], lmax[r]));
                if (__any(need)) {
                    float gn = -__logf(-__logf(urX[f][r] + EPSF) + EPSF);
                    float lg = gn - ds;
                    lmax[r] = fmaxf(lmax[r], lg);
                    if (ds < fminf(r1F[r], d1[r]) + DELTAF) {
                        int slot = atomicAdd((int*)(smem + OFF_DC + rl * 4), 1);
                        if (slot < DCAP) dlists[(size_t)(half * B + grow) * DCAP + slot] = cidx;
                    }
                    if (ds < r1F[r]) atomicMin((unsigned*)(smem + OFF_R1 + rl * 4), fmap(ds));
                    if (lg > fmaxf(rmF[r], lmax[r]) - SKIP) {
                        int slot = atomicAdd((int*)(smem + OFF_CT + rl * 4), 1);
                        if (slot < CAP)
                            lists[(size_t)(half * B + grow) * CAP + slot] =
                                make_int2(__float_as_int(lg), cidx);
                    }
                    if (lg > rmF[r]) atomicMax((unsigned*)(smem + OFF_RM + rl * 4), fmap(lg));
                }
            }
    };

    #pragma unroll 1
    for (int t = 0; t < 64; ++t) {
        const int nb = nb0 + t * 64;
        // u / cnorm loads for this tile (latency covered by GEMM)
        float ur[2][4];
        #pragma unroll
        for (int f = 0; f < 2; ++f)
            #pragma unroll
            for (int r = 0; r < 4; ++r)
                ur[f][r] = ubase[(size_t)r * N + f * 16 + nb];
        float cn0 = cnorm[nb + wn * 32 + l15];
        float cn1 = cnorm[nb + wn * 32 + 16 + l15];

        // GEMM: single-product bf16; 4 independent chains (ks parity x f)
        f32x4 a0e = {0.f,0.f,0.f,0.f}, a0o = {0.f,0.f,0.f,0.f};
        f32x4 a1e = {0.f,0.f,0.f,0.f}, a1o = {0.f,0.f,0.f,0.f};
        #pragma unroll
        for (int ks = 0; ks < 16; ++ks) {
            const int pos = (((ks * 4 + g) ^ xr) << 4);
            bf16x8 b0 = *reinterpret_cast<const bf16x8*>(baseH + pos);
            bf16x8 b1 = *reinterpret_cast<const bf16x8*>(baseH + 16 * 1024 + pos);
            if (ks & 1) {
                a0o = __builtin_amdgcn_mfma_f32_16x16x32_bf16(ah[ks], b0, a0o, 0, 0, 0);
                a1o = __builtin_amdgcn_mfma_f32_16x16x32_bf16(ah[ks], b1, a1o, 0, 0, 0);
            } else {
                a0e = __builtin_amdgcn_mfma_f32_16x16x32_bf16(ah[ks], b0, a0e, 0, 0, 0);
                a1e = __builtin_amdgcn_mfma_f32_16x16x32_bf16(ah[ks], b1, a1e, 0, 0, 0);
            }
        }
        __syncthreads();   // SYNC_Z: all waves done reading B(t)

        // issue DMA for tile t+1 (same buffer); latency hides under the
        // delayed epilogue + dsv work below.
        if (t < 63) stage(nb + 64);

        // delayed heavy epilogue for tile t-1 (independent of GEMM(t))
        if (t >= 2) epi_fast(dsv_prev, ur_prev, nb - 64);

        // dsv for tile t (needs this tile's acc)
        float dsv[2][4];
        #pragma unroll
        for (int f = 0; f < 2; ++f)
            #pragma unroll
            for (int r = 0; r < 4; ++r) {
                float S = f ? (a1e[r] + a1o[r]) : (a0e[r] + a0o[r]);
                dsv[f][r] = xn_r[r] - 2.f * S + (f ? cn1 : cn0);
            }

        if (t == 0) {
            // tile 0: immediate full processing, butterfly-seeded gates
            float lgv0[2][4];
            #pragma unroll
            for (int f = 0; f < 2; ++f)
                #pragma unroll
                for (int r = 0; r < 4; ++r) {
                    float ds = dsv[f][r];
                    float gn = -__logf(-__logf(ur[f][r] + EPSF) + EPSF);
                    lgv0[f][r] = gn - ds;
                    int cidx = nb + wn * 32 + f * 16 + l15;
                    if (ds < d1[r]) { d2[r] = d1[r]; d1[r] = ds; i1[r] = cidx; }
                    else if (ds < d2[r]) d2[r] = ds;
                    lmax[r] = fmaxf(lmax[r], lgv0[f][r]);
                }
            #pragma unroll
            for (int r = 0; r < 4; ++r) {
                float mx = lmax[r], mn = d1[r];
                #pragma unroll
                for (int off = 1; off < 16; off <<= 1) {
                    mx = fmaxf(mx, __shfl_xor(mx, off));
                    mn = fminf(mn, __shfl_xor(mn, off));
                }
                if (l15 == 0) {
                    int rl = wm * 16 + g * 4 + r;
                    atomicMax((unsigned*)(smem + OFF_RM + rl * 4), fmap(mx));
                    atomicMin((unsigned*)(smem + OFF_R1 + rl * 4), fmap(mn));
                }
            }
            __syncthreads();   // gates visible before tile-0 admission
            float rmF[4], r1F[4];
            #pragma unroll
            for (int r = 0; r < 4; ++r) {
                int rl = wm * 16 + g * 4 + r;
                rmF[r] = funmap(*(const unsigned*)(smem + OFF_RM + rl * 4));
                r1F[r] = funmap(*(const unsigned*)(smem + OFF_R1 + rl * 4));
            }
            #pragma unroll
            for (int f = 0; f < 2; ++f)
                #pragma unroll
                for (int r = 0; r < 4; ++r) {
                    const int rl = wm * 16 + g * 4 + r;
                    const int grow = rbase + rl;
                    float ds = dsv[f][r], lg = lgv0[f][r];
                    int cidx = nb + wn * 32 + f * 16 + l15;
                    if (ds < fminf(r1F[r], d1[r]) + DELTAF) {
                        int slot = atomicAdd((int*)(smem + OFF_DC + rl * 4), 1);
                        if (slot < DCAP) dlists[(size_t)(half * B + grow) * DCAP + slot] = cidx;
                    }
                    if (ds < r1F[r]) atomicMin((unsigned*)(smem + OFF_R1 + rl * 4), fmap(ds));
                    if (lg > fmaxf(rmF[r], lmax[r]) - SKIP) {
                        int slot = atomicAdd((int*)(smem + OFF_CT + rl * 4), 1);
                        if (slot < CAP)
                            lists[(size_t)(half * B + grow) * CAP + slot] =
                                make_int2(__float_as_int(lg), cidx);
                    }
                    if (lg > rmF[r]) atomicMax((unsigned*)(smem + OFF_RM + rl * 4), fmap(lg));
                }
        } else {
            // save pipeline state for processing at t+1
            #pragma unroll
            for (int f = 0; f < 2; ++f)
                #pragma unroll
                for (int r = 0; r < 4; ++r) {
                    dsv_prev[f][r] = dsv[f][r];
                    ur_prev[f][r] = ur[f][r];
                }
        }
        __syncthreads();   // SYNC_A: drains DMA(t+1) -> next GEMM safe
    }
    // drain pipeline: tile 63
    epi_fast(dsv_prev, ur_prev, nb0 + 63 * 64);

    // ---- final merge: butterfly over the 16 l15 lanes, then across wn ----
    #pragma unroll
    for (int r = 0; r < 4; ++r) {
        float D1 = d1[r], D2v = d2[r]; int I1 = i1[r];
        #pragma unroll
        for (int off = 1; off < 16; off <<= 1) {
            float o1 = __shfl_xor(D1, off), o2 = __shfl_xor(D2v, off);
            int oi = __shfl_xor(I1, off);
            if (o1 < D1 || (o1 == D1 && oi < I1)) { D2v = fminf(D1, o2); D1 = o1; I1 = oi; }
            else D2v = fminf(o1, D2v);
        }
        if (l15 == 0) {
            int rl = wm * 16 + g * 4 + r;
            *(float*)(smem + OFF_P1 + (wn * 64 + rl) * 4) = D1;
            *(float*)(smem + OFF_P2 + (wn * 64 + rl) * 4) = D2v;
            *(int*)(smem + OFF_PI + (wn * 64 + rl) * 4) = I1;
        }
    }
    __syncthreads();
    if (tid < 64) {
        float a1 = *(float*)(smem + OFF_P1 + tid * 4), a2 = *(float*)(smem + OFF_P2 + tid * 4);
        int ai = *(int*)(smem + OFF_PI + tid * 4);
        float b1 = *(float*)(smem + OFF_P1 + (64 + tid) * 4), b2 = *(float*)(smem + OFF_P2 + (64 + tid) * 4);
        int bi = *(int*)(smem + OFF_PI + (64 + tid) * 4);
        float m1, m2; int mi;
        if (b1 < a1 || (b1 == a1 && bi < ai)) { m1 = b1; mi = bi; m2 = fminf(a1, b2); }
        else                                  { m1 = a1; mi = ai; m2 = fminf(b1, a2); }
        int hrow = half * B + rbase + tid;
        m1h[hrow] = m1; m2h[hrow] = m2; i1h[hrow] = mi;
        counts[hrow] = *(int*)(smem + OFF_CT + tid * 4);    // RAW (overflow detect)
        dcounts[hrow] = *(int*)(smem + OFF_DC + tid * 4);   // RAW (overflow detect)
    }
}

// ---- finalize: softmax over candidate lists -> quantized, loss; merge top2
__global__ __launch_bounds__(256) void vq_finalize(
        const float* __restrict__ cb, const float* __restrict__ x,
        const int2* __restrict__ lists, const int* __restrict__ counts,
        float* __restrict__ m1h, float* __restrict__ m2h, int* __restrict__ i1h,
        float* __restrict__ out_q, float* __restrict__ out_loss) {
    __shared__ int2 ebuf[4][2 * CAP];
    int w = threadIdx.x >> 6, lane = threadIdx.x & 63;
    int row = blockIdx.x * 4 + w;
    int n0 = counts[row];      if (n0 > CAP) n0 = CAP;
    int n1 = counts[B + row];  if (n1 > CAP) n1 = CAP;
    int n = n0 + n1;
    for (int e = lane; e < n0; e += 64) ebuf[w][e] = lists[(size_t)row * CAP + e];
    for (int e = lane; e < n1; e += 64) ebuf[w][n0 + e] = lists[(size_t)(B + row) * CAP + e];
    __syncthreads();
    float m = -INFINITY;
    for (int e = lane; e < n; e += 64) m = fmaxf(m, __int_as_float(ebuf[w][e].x));
    #pragma unroll
    for (int off = 1; off < 64; off <<= 1) m = fmaxf(m, __shfl_xor(m, off));
    float denom = 0.f;
    for (int e = lane; e < n; e += 64) denom += __expf(__int_as_float(ebuf[w][e].x) - m);
    #pragma unroll
    for (int off = 1; off < 64; off <<= 1) denom += __shfl_xor(denom, off);
    float q[8] = {0.f, 0.f, 0.f, 0.f, 0.f, 0.f, 0.f, 0.f};
    for (int e = 0; e < n; ++e) {
        int2 ent = ebuf[w][e];
        float wgt = __expf(__int_as_float(ent.x) - m);
        if (wgt < 1e-9f) continue;   // negligible entry: skip codebook read
        const float4* c4 = reinterpret_cast<const float4*>(cb + (size_t)ent.y * D + lane * 8);
        float4 c0 = c4[0], c1 = c4[1];
        q[0] += wgt * c0.x; q[1] += wgt * c0.y; q[2] += wgt * c0.z; q[3] += wgt * c0.w;
        q[4] += wgt * c1.x; q[5] += wgt * c1.y; q[6] += wgt * c1.z; q[7] += wgt * c1.w;
    }
    float inv = 1.f / denom;
    const float4* x4 = reinterpret_cast<const float4*>(x + (size_t)row * D + lane * 8);
    float4 xa = x4[0], xb = x4[1];
    float xs[8] = {xa.x, xa.y, xa.z, xa.w, xb.x, xb.y, xb.z, xb.w};
    float ls = 0.f;
    #pragma unroll
    for (int k = 0; k < 8; ++k) {
        q[k] *= inv;
        float dlt = xs[k] - q[k];
        ls += dlt * dlt;
    }
    float4 q0 = {q[0], q[1], q[2], q[3]}, q1 = {q[4], q[5], q[6], q[7]};
    float4* o = reinterpret_cast<float4*>(out_q + (size_t)row * D + lane * 8);
    o[0] = q0; o[1] = q1;
    #pragma unroll
    for (int off = 1; off < 64; off <<= 1) ls += __shfl_xor(ls, off);
    if (lane == 0) {
        out_loss[row] = 1.25f * ls;
        float a1 = m1h[row], a2 = m2h[row]; int ai = i1h[row];
        float b1 = m1h[B + row], b2 = m2h[B + row]; int bi = i1h[B + row];
        float mm1, mm2; int mi;
        if (b1 < a1 || (b1 == a1 && bi < ai)) { mm1 = b1; mi = bi; mm2 = fminf(a1, b2); }
        else                                  { mm1 = a1; mi = ai; mm2 = fminf(b1, a2); }
        m1h[row] = mm1; m2h[row] = mm2; i1h[row] = mi;
    }
}

// ---- full-row softmax fallback for logit-list overflow (expected: 0 rows)
__global__ __launch_bounds__(256) void vq_row_full(
        const float* __restrict__ x, const float* __restrict__ cb,
        const float* __restrict__ cnorm, const float* __restrict__ u,
        const int* __restrict__ counts,
        float* __restrict__ out_q, float* __restrict__ out_loss) {
    int row = blockIdx.x;
    if (counts[row] <= CAP && counts[B + row] <= CAP) return;
    int tid = threadIdx.x, wv_ = tid >> 6, lane = tid & 63;
    __shared__ float xs[D];
    __shared__ float red[4];
    __shared__ float wts[256]; __shared__ int ids[256]; __shared__ int nc;
    for (int i = tid; i < D; i += 256) xs[i] = x[(size_t)row * D + i];
    if (tid == 0) nc = 0;
    __syncthreads();
    float xn = 0.f;
    for (int i = tid; i < D; i += 256) xn += xs[i] * xs[i];
    #pragma unroll
    for (int off = 1; off < 64; off <<= 1) xn += __shfl_xor(xn, off);
    if (lane == 0) red[wv_] = xn;
    __syncthreads();
    xn = red[0] + red[1] + red[2] + red[3];
    __syncthreads();
    float m = -INFINITY;
    for (int n = tid; n < N; n += 256) {
        float dot = 0.f;
        const float* c = cb + (size_t)n * D;
        for (int d = 0; d < D; ++d) dot = fmaf(xs[d], c[d], dot);
        float lg = -__logf(-__logf(u[(size_t)row * N + n] + EPSF) + EPSF)
                 - (xn - 2.f * dot + cnorm[n]);
        m = fmaxf(m, lg);
    }
    #pragma unroll
    for (int off = 1; off < 64; off <<= 1) m = fmaxf(m, __shfl_xor(m, off));
    if (lane == 0) red[wv_] = m;
    __syncthreads();
    m = fmaxf(fmaxf(red[0], red[1]), fmaxf(red[2], red[3]));
    __syncthreads();
    float denom = 0.f;
    for (int n = tid; n < N; n += 256) {
        float dot = 0.f;
        const float* c = cb + (size_t)n * D;
        for (int d = 0; d < D; ++d) dot = fmaf(xs[d], c[d], dot);
        float lg = -__logf(-__logf(u[(size_t)row * N + n] + EPSF) + EPSF)
                 - (xn - 2.f * dot + cnorm[n]);
        float wv2 = __expf(lg - m);
        denom += wv2;
        if (wv2 > 1e-8f) {
            int s = atomicAdd(&nc, 1);
            if (s < 256) { wts[s] = wv2; ids[s] = n; }
        }
    }
    #pragma unroll
    for (int off = 1; off < 64; off <<= 1) denom += __shfl_xor(denom, off);
    if (lane == 0) red[wv_] = denom;
    __syncthreads();
    denom = red[0] + red[1] + red[2] + red[3];
    int ncl = nc < 256 ? nc : 256;
    float q0 = 0.f, q1 = 0.f;
    for (int e = 0; e < ncl; ++e) {
        const float* c = cb + (size_t)ids[e] * D;
        q0 += wts[e] * c[tid * 2];
        q1 += wts[e] * c[tid * 2 + 1];
    }
    q0 /= denom; q1 /= denom;
    out_q[(size_t)row * D + tid * 2] = q0;
    out_q[(size_t)row * D + tid * 2 + 1] = q1;
    float dl0 = xs[tid * 2] - q0, dl1 = xs[tid * 2 + 1] - q1;
    float ls = dl0 * dl0 + dl1 * dl1;
    #pragma unroll
    for (int off = 1; off < 64; off <<= 1) ls += __shfl_xor(ls, off);
    __syncthreads();
    if (lane == 0) red[wv_] = ls;
    __syncthreads();
    if (tid == 0) out_loss[row] = 1.25f * (red[0] + red[1] + red[2] + red[3]);
}

// ---- candidate-based f64 argmin recheck (one wave per row) --------------
__global__ __launch_bounds__(256) void argmin_fix2(
        const float* __restrict__ x, const float* __restrict__ cb,
        const float* __restrict__ m1h, const float* __restrict__ m2h,
        const int* __restrict__ i1h,
        const int* __restrict__ dcounts, const int* __restrict__ dlists,
        float* __restrict__ out_ind) {
    int w = threadIdx.x >> 6, lane = threadIdx.x & 63;
    int row = blockIdx.x * 4 + w;
    if (m2h[row] - m1h[row] >= DELTAF) {
        if (lane == 0) out_ind[row] = (float)i1h[row];
        return;
    }
    const float4* x4 = reinterpret_cast<const float4*>(x + (size_t)row * D) + lane * 2;
    float4 xa = x4[0], xb = x4[1];
    double xd[8] = {(double)xa.x, (double)xa.y, (double)xa.z, (double)xa.w,
                    (double)xb.x, (double)xb.y, (double)xb.z, (double)xb.w};
    double bestv = 1e300; int besti = 0x7fffffff;

    auto evalCode = [&](int n) {
        const float4* c4 = reinterpret_cast<const float4*>(cb + (size_t)n * D) + lane * 2;
        float4 ca = c4[0], cbv = c4[1];
        double cd[8] = {(double)ca.x, (double)ca.y, (double)ca.z, (double)ca.w,
                        (double)cbv.x, (double)cbv.y, (double)cbv.z, (double)cbv.w};
        double s = 0.0;
        #pragma unroll
        for (int k = 0; k < 8; ++k) {
            double dlt = xd[k] - cd[k];
            s = fma(dlt, dlt, s);
        }
        #pragma unroll
        for (int off = 1; off < 64; off <<= 1) s += __shfl_xor(s, off);
        if (s < bestv || (s == bestv && n < besti)) { bestv = s; besti = n; }
    };

    int n0 = dcounts[row], n1 = dcounts[B + row];
    if (n0 <= DCAP && n1 <= DCAP) {
        evalCode(i1h[row]);   // hardening: never worse than the bf16 argmin
        for (int e = 0; e < n0; ++e) evalCode(dlists[(size_t)row * DCAP + e]);
        for (int e = 0; e < n1; ++e) evalCode(dlists[(size_t)(B + row) * DCAP + e]);
    } else {
        for (int n = 0; n < N; ++n) evalCode(n);   // rare overflow fallback
    }
    if (lane == 0) out_ind[row] = (float)besti;
}

// ======================= FALLBACK PATH (round-1, passing) =================
constexpr int ROWS = 16;
constexpr int NT   = 256;
constexpr int DT   = 16;

__global__ __launch_bounds__(256) void prep_norms(const float* __restrict__ x,
                                                  const float* __restrict__ cb,
                                                  float* __restrict__ cnorm,
                                                  float* __restrict__ xnorm) {
    int wave = threadIdx.x >> 6, lane = threadIdx.x & 63;
    int v = blockIdx.x * 4 + wave;
    const float* src;
    float* dst;
    if (v < N) { src = cb + (size_t)v * D; dst = cnorm + v; }
    else       { int b = v - N; if (b >= B) return; src = x + (size_t)b * D; dst = xnorm + b; }
    const float4* s4 = reinterpret_cast<const float4*>(src) + lane * 2;
    float4 a = s4[0], c = s4[1];
    float s = a.x*a.x + a.y*a.y + a.z*a.z + a.w*a.w
            + c.x*c.x + c.y*c.y + c.z*c.z + c.w*c.w;
    #pragma unroll
    for (int off = 1; off < 64; off <<= 1) s += __shfl_xor(s, off);
    if (lane == 0) *dst = s;
}

__global__ __launch_bounds__(256) void vq_main(const float* __restrict__ x,
        const float* __restrict__ cb, const float* __restrict__ u,
        const float* __restrict__ cnorm, const float* __restrict__ xnorm,
        float* __restrict__ out_q, float* __restrict__ out_loss,
        float* __restrict__ m1w, float* __restrict__ m2w, int* __restrict__ i1w) {

    __shared__ float xs[ROWS][D];
    __shared__ float ct[DT][NT];

    const int tid  = threadIdx.x;
    const int wave = tid >> 6, lane = tid & 63;
    const int rbase = blockIdx.x * ROWS;
    const int wrow  = rbase + wave * 4;

    for (int i = tid; i < ROWS * (D / 4); i += 256)
        reinterpret_cast<float4*>(xs)[i] =
            reinterpret_cast<const float4*>(x + (size_t)rbase * D)[i];
    __syncthreads();

    float xn[4];
    #pragma unroll
    for (int r = 0; r < 4; ++r) xn[r] = xnorm[wrow + r];

    float m[4], denom[4], acc[4][8];
    float am1[4], am2[4]; int ai1[4];
    #pragma unroll
    for (int r = 0; r < 4; ++r) {
        m[r] = -INFINITY; denom[r] = 0.f;
        am1[r] = INFINITY; am2[r] = INFINITY; ai1[r] = 0;
        #pragma unroll
        for (int k = 0; k < 8; ++k) acc[r][k] = 0.f;
    }

    for (int nb = 0; nb < N; nb += NT) {
        float S[4][4];
        #pragma unroll
        for (int r = 0; r < 4; ++r)
            #pragma unroll
            for (int j = 0; j < 4; ++j) S[r][j] = 0.f;

        for (int db = 0; db < D; db += DT) {
            __syncthreads();
            {
                const float4* src = reinterpret_cast<const float4*>(
                        cb + (size_t)(nb + tid) * D + db);
                float4 a0 = src[0], a1 = src[1], a2 = src[2], a3 = src[3];
                ct[ 0][tid]=a0.x; ct[ 1][tid]=a0.y; ct[ 2][tid]=a0.z; ct[ 3][tid]=a0.w;
                ct[ 4][tid]=a1.x; ct[ 5][tid]=a1.y; ct[ 6][tid]=a1.z; ct[ 7][tid]=a1.w;
                ct[ 8][tid]=a2.x; ct[ 9][tid]=a2.y; ct[10][tid]=a2.z; ct[11][tid]=a2.w;
                ct[12][tid]=a3.x; ct[13][tid]=a3.y; ct[14][tid]=a3.z; ct[15][tid]=a3.w;
            }
            __syncthreads();
            #pragma unroll
            for (int dq = 0; dq < DT / 4; ++dq) {
                float creg[4][4];
                #pragma unroll
                for (int k = 0; k < 4; ++k) {
                    float4 cv = *reinterpret_cast<const float4*>(&ct[dq*4 + k][4*lane]);
                    creg[k][0]=cv.x; creg[k][1]=cv.y; creg[k][2]=cv.z; creg[k][3]=cv.w;
                }
                #pragma unroll
                for (int r = 0; r < 4; ++r) {
                    float4 xv = *reinterpret_cast<const float4*>(&xs[wave*4 + r][db + dq*4]);
                    float xr[4] = {xv.x, xv.y, xv.z, xv.w};
                    #pragma unroll
                    for (int k = 0; k < 4; ++k)
                        #pragma unroll
                        for (int j = 0; j < 4; ++j)
                            S[r][j] = fmaf(xr[k], creg[k][j], S[r][j]);
                }
            }
        }

        float4 cn4 = *reinterpret_cast<const float4*>(&cnorm[nb + 4*lane]);
        float cn[4] = {cn4.x, cn4.y, cn4.z, cn4.w};

        float logit[4][4], dist[4][4];
        #pragma unroll
        for (int r = 0; r < 4; ++r) {
            float4 u4 = *reinterpret_cast<const float4*>(
                    &u[(size_t)(wrow + r) * N + nb + 4*lane]);
            float uu[4] = {u4.x, u4.y, u4.z, u4.w};
            #pragma unroll
            for (int j = 0; j < 4; ++j) {
                float ds = xn[r] - 2.f * S[r][j] + cn[j];
                float gg  = -logf(-logf(uu[j] + EPSF) + EPSF);
                dist[r][j]  = ds;
                logit[r][j] = gg - ds;
            }
        }

        #pragma unroll
        for (int r = 0; r < 4; ++r) {
            float l1 = INFINITY, l2 = INFINITY; int li = 0;
            #pragma unroll
            for (int j = 0; j < 4; ++j) {
                float dv = dist[r][j]; int idx = nb + 4*lane + j;
                if (dv < l1)      { l2 = l1; l1 = dv; li = idx; }
                else if (dv < l2) { l2 = dv; }
            }
            #pragma unroll
            for (int off = 1; off < 64; off <<= 1) {
                float o1 = __shfl_xor(l1, off), o2 = __shfl_xor(l2, off);
                int   oi = __shfl_xor(li, off);
                if (o1 < l1 || (o1 == l1 && oi < li)) { l2 = fminf(l1, o2); l1 = o1; li = oi; }
                else                                  { l2 = fminf(o1, l2); }
            }
            if (l1 < am1[r] || (l1 == am1[r] && li < ai1[r])) {
                am2[r] = fminf(am1[r], l2); am1[r] = l1; ai1[r] = li;
            } else {
                am2[r] = fminf(am2[r], l1);
            }

            float lm = fmaxf(fmaxf(logit[r][0], logit[r][1]),
                             fmaxf(logit[r][2], logit[r][3]));
            #pragma unroll
            for (int off = 1; off < 64; off <<= 1) lm = fmaxf(lm, __shfl_xor(lm, off));
            if (lm > m[r]) {
                float s = expf(m[r] - lm);
                denom[r] *= s;
                #pragma unroll
                for (int k = 0; k < 8; ++k) acc[r][k] *= s;
                m[r] = lm;
            }

            float wv[4];
            #pragma unroll
            for (int j = 0; j < 4; ++j) {
                float e = logit[r][j] - m[r];
                bool act = e > -SKIP;
                wv[j] = act ? expf(e) : 0.f;
                denom[r] += wv[j];
            }
            #pragma unroll
            for (int j = 0; j < 4; ++j) {
                unsigned long long mk = __ballot(wv[j] > 0.f);
                while (mk) {
                    int L = __ffsll((unsigned long long)mk) - 1;
                    mk &= mk - 1;
                    float wb = __shfl(wv[j], L);
                    int nstar = nb + 4*L + j;
                    const float4* crow = reinterpret_cast<const float4*>(
                            cb + (size_t)nstar * D + 8*lane);
                    float4 c0 = crow[0], c1 = crow[1];
                    acc[r][0] = fmaf(wb, c0.x, acc[r][0]);
                    acc[r][1] = fmaf(wb, c0.y, acc[r][1]);
                    acc[r][2] = fmaf(wb, c0.z, acc[r][2]);
                    acc[r][3] = fmaf(wb, c0.w, acc[r][3]);
                    acc[r][4] = fmaf(wb, c1.x, acc[r][4]);
                    acc[r][5] = fmaf(wb, c1.y, acc[r][5]);
                    acc[r][6] = fmaf(wb, c1.z, acc[r][6]);
                    acc[r][7] = fmaf(wb, c1.w, acc[r][7]);
                }
            }
        }
    }

    #pragma unroll
    for (int r = 0; r < 4; ++r) {
        float dn = denom[r];
        #pragma unroll
        for (int off = 1; off < 64; off <<= 1) dn += __shfl_xor(dn, off);
        float inv = 1.f / dn;
        int row = wrow + r;
        float q[8]; float ls = 0.f;
        #pragma unroll
        for (int k = 0; k < 8; ++k) {
            q[k] = acc[r][k] * inv;
            float dlt = xs[wave*4 + r][8*lane + k] - q[k];
            ls += dlt * dlt;
        }
        float4 q0 = {q[0], q[1], q[2], q[3]}, q1 = {q[4], q[5], q[6], q[7]};
        float4* o = reinterpret_cast<float4*>(out_q + (size_t)row * D + 8*lane);
        o[0] = q0; o[1] = q1;
        #pragma unroll
        for (int off = 1; off < 64; off <<= 1) ls += __shfl_xor(ls, off);
        if (lane == 0) {
            out_loss[row] = 1.25f * ls;
            m1w[row] = am1[r]; m2w[row] = am2[r]; i1w[row] = ai1[r];
        }
    }
}

// ---- full-scan f64 argmin recheck (fallback path only) -------------------
__global__ __launch_bounds__(256) void argmin_fix(const float* __restrict__ x,
        const float* __restrict__ cb, const float* __restrict__ m1w,
        const float* __restrict__ m2w, const int* __restrict__ i1w,
        float* __restrict__ out_ind) {
    int b = blockIdx.x, tid = threadIdx.x;
    if (m2w[b] - m1w[b] >= DELTA) {
        if (tid == 0) out_ind[b] = (float)i1w[b];
        return;
    }
    __shared__ double xsd[D];
    for (int i = tid; i < D; i += 256) xsd[i] = (double)x[(size_t)b * D + i];
    __syncthreads();
    double xn = 0.0;
    for (int d = 0; d < D; ++d) xn += xsd[d] * xsd[d];

    double bestv = 1e300; int besti = N;
    for (int n = tid; n < N; n += 256) {
        const float* c = cb + (size_t)n * D;
        double d0 = 0.0, d1v = 0.0, c0 = 0.0, c1v = 0.0;
        for (int d = 0; d < D; d += 2) {
            double ca = (double)c[d], cbv = (double)c[d + 1];
            d0 += xsd[d] * ca;  c0 += ca * ca;
            d1v += xsd[d + 1] * cbv; c1v += cbv * cbv;
        }
        double dv = xn - 2.0 * (d0 + d1v) + (c0 + c1v);
        if (dv < bestv || (dv == bestv && n < besti)) { bestv = dv; besti = n; }
    }
    __shared__ double rv[256]; __shared__ int ri[256];
    rv[tid] = bestv; ri[tid] = besti;
    __syncthreads();
    for (int s = 128; s > 0; s >>= 1) {
        if (tid < s) {
            if (rv[tid+s] < rv[tid] || (rv[tid+s] == rv[tid] && ri[tid+s] < ri[tid])) {
                rv[tid] = rv[tid+s]; ri[tid] = ri[tid+s];
            }
        }
        __syncthreads();
    }
    if (tid == 0) out_ind[b] = (float)ri[0];
}

// ---------------- host launch --------------------------------------------
extern "C" void kernel_launch(void* const* d_in, const int* in_sizes, int n_in,
                              void* d_out, int out_size, void* d_ws, size_t ws_size,
                              hipStream_t stream) {
    const float* x  = (const float*)d_in[0];
    const float* cb = (const float*)d_in[1];
    const float* u  = (const float*)d_in[2];
    float* out      = (float*)d_out;
    float* out_q    = out;
    float* out_ind  = out + (size_t)B * D;
    float* out_loss = out_ind + B;

    // fast-path workspace layout (bytes)
    const size_t O_CH = 0;
    const size_t O_CN = O_CH + (size_t)N * D * 2;          // 8 MB
    const size_t O_XN = O_CN + (size_t)N * 4;
    const size_t O_M1 = O_XN + (size_t)B * 4;
    const size_t O_M2 = O_M1 + (size_t)2 * B * 4;
    const size_t O_I1 = O_M2 + (size_t)2 * B * 4;
    const size_t O_CT = O_I1 + (size_t)2 * B * 4;
    const size_t O_DC = O_CT + (size_t)2 * B * 4;
    const size_t O_LS = O_DC + (size_t)2 * B * 4;
    const size_t O_DL = O_LS + (size_t)2 * B * CAP * 8;    // 12.6 MB
    const size_t NEED = O_DL + (size_t)2 * B * DCAP * 4;   // ~24.5 MB

    if (ws_size >= NEED) {
        char* w8 = (char*)d_ws;
        unsigned short* ch = (unsigned short*)(w8 + O_CH);
        float* cnorm = (float*)(w8 + O_CN);
        float* xnorm = (float*)(w8 + O_XN);
        float* m1h   = (float*)(w8 + O_M1);
        float* m2h   = (float*)(w8 + O_M2);
        int*   i1h   = (int*)(w8 + O_I1);
        int*   counts= (int*)(w8 + O_CT);
        int*   dcounts=(int*)(w8 + O_DC);
        int2*  lists = (int2*)(w8 + O_LS);
        int*   dlists= (int*)(w8 + O_DL);

        hipLaunchKernelGGL(vq_prep, dim3((N + B) / 4), dim3(256), 0, stream,
                           x, cb, ch, cnorm, xnorm, counts, dcounts);
        hipLaunchKernelGGL(vq_mfma, dim3(256), dim3(512), 0, stream,
                           x, ch, cnorm, xnorm, u, lists, counts,
                           dlists, dcounts, m1h, m2h, i1h);
        hipLaunchKernelGGL(vq_finalize, dim3(B / 4), dim3(256), 0, stream,
                           cb, x, lists, counts, m1h, m2h, i1h, out_q, out_loss);
        hipLaunchKernelGGL(vq_row_full, dim3(B), dim3(256), 0, stream,
                           x, cb, cnorm, u, counts, out_q, out_loss);
        hipLaunchKernelGGL(argmin_fix2, dim3(B / 4), dim3(256), 0, stream,
                           x, cb, m1h, m2h, i1h, dcounts, dlists, out_ind);
    } else {
        float* ws    = (float*)d_ws;
        float* cnorm = ws;
        float* xnorm = ws + N;
        float* m1w   = xnorm + B;
        float* m2w   = m1w + B;
        int*   i1w   = (int*)(m2w + B);

        hipLaunchKernelGGL(prep_norms, dim3((N + B) / 4), dim3(256), 0, stream,
                           x, cb, cnorm, xnorm);
        hipLaunchKernelGGL(vq_main, dim3(B / ROWS), dim3(256), 0, stream,
                           x, cb, u, cnorm, xnorm, out_q, out_loss, m1w, m2w, i1w);
        hipLaunchKernelGGL(argmin_fix, dim3(B), dim3(256), 0, stream,
                           x, cb, m1w, m2w, i1w, out_ind);
    }
}